// Round 4
// baseline (193.590 us; speedup 1.0000x reference)
//
#include <hip/hip_runtime.h>
#include <hip/hip_bf16.h>

// Problem constants: B=2, S=2048, D=1024, H=16, dk=64
#define S_LEN 2048
#define D_DIM 1024
#define N_HEADS 16
#define M_ROWS 4096  // B*S

typedef __bf16 bf16x8 __attribute__((ext_vector_type(8)));
typedef float f32x4 __attribute__((ext_vector_type(4)));
typedef unsigned short ushortx8 __attribute__((ext_vector_type(8)));

__device__ __forceinline__ unsigned short f2bf(float f) {
  unsigned int u = __builtin_bit_cast(unsigned int, f);
  u += 0x7fffu + ((u >> 16) & 1u);   // RNE
  return (unsigned short)(u >> 16);
}

__device__ __forceinline__ bf16x8 load8(const unsigned short* p) {
  return __builtin_bit_cast(bf16x8, *(const ushortx8*)p);
}

__device__ __forceinline__ void gload16(const unsigned short* g, unsigned short* l) {
  __builtin_amdgcn_global_load_lds((const __attribute__((address_space(1))) void*)g,
                                   (__attribute__((address_space(3))) void*)l,
                                   16, 0, 0);
}

// ---------------- fp32 -> bf16 convert (fused: x + 4 weights) ----------------
__global__ void cvt5_kernel(const float* __restrict__ s0, const float* __restrict__ s1,
                            const float* __restrict__ s2, const float* __restrict__ s3,
                            const float* __restrict__ s4,
                            unsigned short* __restrict__ d0, unsigned short* __restrict__ d1,
                            unsigned short* __restrict__ d2, unsigned short* __restrict__ d3,
                            unsigned short* __restrict__ d4,
                            int n4x, int n4w) {
  const int y = blockIdx.y;
  const float* s = (y == 0) ? s0 : (y == 1) ? s1 : (y == 2) ? s2 : (y == 3) ? s3 : s4;
  unsigned short* d = (y == 0) ? d0 : (y == 1) ? d1 : (y == 2) ? d2 : (y == 3) ? d3 : d4;
  const int n4 = (y == 0) ? n4x : n4w;
  int i = blockIdx.x * blockDim.x + threadIdx.x;
  if (i < n4) {
    float4 f = ((const float4*)s)[i];
    unsigned short a = f2bf(f.x), b = f2bf(f.y), c = f2bf(f.z), dd = f2bf(f.w);
    unsigned long long packed = (unsigned long long)a | ((unsigned long long)b << 16)
                              | ((unsigned long long)c << 32) | ((unsigned long long)dd << 48);
    ((unsigned long long*)d)[i] = packed;
  }
}

// ---------------- bf16 GEMM: C = A[M,K] * B[N,K]^T ----------------
// mode 0: fp32 row-major [M][N] output
// mode 1: bf16 [B,H,S,64] output (Q,K); Q (z==0) pre-scaled by 1/sqrt(dk)
// mode 2: bf16 [B,H,64,S] output (V transposed)
__global__ __launch_bounds__(256) void gemm_bt(
    const unsigned short* __restrict__ A,
    const unsigned short* __restrict__ B0,
    const unsigned short* __restrict__ B1,
    const unsigned short* __restrict__ B2,
    void* __restrict__ C0, void* __restrict__ C1, void* __restrict__ C2,
    int M, int N, int K, int modesel)
{
  __shared__ __align__(16) unsigned short At[128 * 64];
  __shared__ __align__(16) unsigned short Bt[128 * 64];

  const int z = blockIdx.z;
  const unsigned short* Bp = (z == 0) ? B0 : (z == 1) ? B1 : B2;
  void* Cp = (z == 0) ? C0 : (z == 1) ? C1 : C2;
  const int mode = (modesel == 0) ? 0 : ((z == 2) ? 2 : 1);
  const float escale = (modesel == 1 && z == 0) ? 0.125f : 1.0f;

  const int tid = threadIdx.x;
  const int lane = tid & 63, wave = tid >> 6;
  const int bm = blockIdx.y * 128, bn = blockIdx.x * 128;
  const int wr = wave >> 1, wc = wave & 1;           // 2x2 wave grid, 64x64 each
  const int cl = lane & 15, g = lane >> 4;
  // staging: chunks of 512 elems (8 rows x 64 elems); pre-swizzled global slot
  const int ci = lane >> 3, si = lane & 7;
  const int sg = si ^ (ci & 7);

  f32x4 acc[4][4] = {};

  for (int kb = 0; kb < K; kb += 64) {
    __syncthreads();
#pragma unroll
    for (int cc = 0; cc < 4; ++cc) {
      int chunk = wave * 4 + cc;
      int row = chunk * 8 + ci;
      gload16(A  + (size_t)(bm + row) * K + kb + sg * 8, &At[chunk * 512]);
      gload16(Bp + (size_t)(bn + row) * K + kb + sg * 8, &Bt[chunk * 512]);
    }
    __syncthreads();
#pragma unroll
    for (int kc = 0; kc < 2; ++kc) {
      bf16x8 af[4], bfr[4];
#pragma unroll
      for (int mi = 0; mi < 4; ++mi) {
        int row = wr * 64 + mi * 16 + cl;
        int slot = (kc * 4 + g) ^ (row & 7);
        af[mi] = load8(&At[row * 64 + slot * 8]);
      }
#pragma unroll
      for (int ni = 0; ni < 4; ++ni) {
        int row = wc * 64 + ni * 16 + cl;
        int slot = (kc * 4 + g) ^ (row & 7);
        bfr[ni] = load8(&Bt[row * 64 + slot * 8]);
      }
#pragma unroll
      for (int mi = 0; mi < 4; ++mi)
#pragma unroll
        for (int ni = 0; ni < 4; ++ni)
          acc[mi][ni] = __builtin_amdgcn_mfma_f32_16x16x32_bf16(af[mi], bfr[ni], acc[mi][ni], 0, 0, 0);
    }
  }

  // epilogue: C row = (lane>>4)*4 + reg, col = lane&15
  const int r0 = g * 4;
#pragma unroll
  for (int mi = 0; mi < 4; ++mi) {
#pragma unroll
    for (int ni = 0; ni < 4; ++ni) {
      int mg = bm + wr * 64 + mi * 16 + r0;
      int ng = bn + wc * 64 + ni * 16 + cl;
#pragma unroll
      for (int r = 0; r < 4; ++r) {
        float v = acc[mi][ni][r] * escale;
        int m = mg + r;
        if (mode == 0) {
          ((float*)Cp)[(size_t)m * N + ng] = v;
        } else {
          int b = m >> 11, s = m & 2047;        // S=2048
          int h = ng >> 6, d = ng & 63;         // dk=64
          unsigned short* o = (unsigned short*)Cp;
          if (mode == 1) o[((size_t)(b * N_HEADS + h) * S_LEN + s) * 64 + d] = f2bf(v);
          else           o[((size_t)(b * N_HEADS + h) * 64 + d) * S_LEN + s] = f2bf(v);
        }
      }
    }
  }
}

// ---------------- causal flash attention: swapped-QK + split-K ---------------
// Q,K: [BH][S][64] bf16 (Q pre-scaled); Vt: [BH][64][S] bf16; out: [B][S][H*64] bf16
// 1024 blocks x 4 waves. Block owns 64 q-rows (2 pairs of waves). Within a pair,
// wave half=0 takes the low half of the key range (no mask), half=1 takes the
// high half (owns the diagonal). Partials merged in LDS after one barrier.
#define PSTR 40   // padded P row stride (elems)

__global__ __launch_bounds__(256, 4) void attn_kernel(
    const unsigned short* __restrict__ Qg,
    const unsigned short* __restrict__ Kg,
    const unsigned short* __restrict__ Vtg,
    unsigned short* __restrict__ Og)
{
  __shared__ __align__(16) unsigned short Pt[4][32 * PSTR];  // per-wave P buffer
  __shared__ __align__(16) float Af[4][32];                  // per-wave alpha transpose
  __shared__ __align__(16) float Mo[2][8][64][4];            // half=1 o frags [pair][rt*4+nt][lane]
  __shared__ __align__(16) float Mq[4][32], Lq[4][32];       // per-wave m,l (q-layout)

  const int tid = threadIdx.x;
  const int lane = tid & 63, wave = tid >> 6;
  const int cl = lane & 15, g = lane >> 4;
  const int pair = wave >> 1, half = wave & 1;

  // XCD-contiguous swizzle; heavy q-chunks first within each bh
  const int wg = (blockIdx.x & 7) * 128 + (blockIdx.x >> 3);
  const int bh = wg >> 5;               // 32 (b,h) pairs, 4 per XCD
  const int qc = 31 - (wg & 31);        // 64-row chunks, descending work order
  const int qt = qc * 64 + pair * 32;   // this pair's 32 q-rows

  const size_t qkb = (size_t)bh * S_LEN;
  unsigned short* P = &Pt[wave][0];
  float* AF = &Af[wave][0];

  const int nkb = qt / 32 + 1;
  const int kmid = nkb >> 1;
  const int kb0 = half ? kmid : 0;
  const int kb1 = half ? nkb : kmid;

  // Q fragments in registers (already scaled by 1/8)
  bf16x8 aq[2][2];
#pragma unroll
  for (int rt = 0; rt < 2; ++rt)
#pragma unroll
    for (int kh = 0; kh < 2; ++kh)
      aq[rt][kh] = load8(Qg + (qkb + qt + rt * 16 + cl) * 64 + kh * 32 + g * 8);

  f32x4 o[2][4] = {};
  float mrow[2] = {-1e30f, -1e30f};
  float lrow[2] = {0.f, 0.f};

  // K fragment double-buffer
  bf16x8 kc[2][2], kn[2][2];
#pragma unroll
  for (int ct = 0; ct < 2; ++ct)
#pragma unroll
    for (int kh = 0; kh < 2; ++kh)
      kc[ct][kh] = load8(Kg + (qkb + kb0 * 32 + ct * 16 + cl) * 64 + kh * 32 + g * 8);

  for (int kb = kb0; kb < kb1; ++kb) {
    const int kbase = kb * 32;

    // V^T fragments for THIS block (used far below -> latency hidden)
    bf16x8 bv[4];
#pragma unroll
    for (int nt = 0; nt < 4; ++nt)
      bv[nt] = load8(Vtg + ((size_t)bh * 64 + nt * 16 + cl) * S_LEN + kbase + g * 8);
    // prefetch K for next block
    {
      int nb = (kb + 1 < kb1) ? kbase + 32 : kbase;
#pragma unroll
      for (int ct = 0; ct < 2; ++ct)
#pragma unroll
        for (int kh = 0; kh < 2; ++kh)
          kn[ct][kh] = load8(Kg + (qkb + nb + ct * 16 + cl) * 64 + kh * 32 + g * 8);
    }

    // swapped scores: Ct[k][q] = K·Q^T; lane holds q=rt*16+cl, k=ct*16+g*4+r
    f32x4 c[2][2] = {};
#pragma unroll
    for (int rt = 0; rt < 2; ++rt)
#pragma unroll
      for (int ct = 0; ct < 2; ++ct) {
        c[rt][ct] = __builtin_amdgcn_mfma_f32_16x16x32_bf16(kc[ct][0], aq[rt][0], c[rt][ct], 0, 0, 0);
        c[rt][ct] = __builtin_amdgcn_mfma_f32_16x16x32_bf16(kc[ct][1], aq[rt][1], c[rt][ct], 0, 0, 0);
      }

    if (half && kb == nkb - 1) {   // diagonal block (only the high wave sees it)
#pragma unroll
      for (int rt = 0; rt < 2; ++rt) {
        int q = qt + rt * 16 + cl;
#pragma unroll
        for (int ct = 0; ct < 2; ++ct) {
          int k0 = kbase + ct * 16 + g * 4;
#pragma unroll
          for (int r = 0; r < 4; ++r)
            if (k0 + r > q) c[rt][ct][r] = -1e30f;
        }
      }
    }

    // row max over k: in-register + 2-step butterfly over g-groups
    float pm[2];
#pragma unroll
    for (int rt = 0; rt < 2; ++rt) {
      float a0 = fmaxf(fmaxf(c[rt][0][0], c[rt][0][1]), fmaxf(c[rt][0][2], c[rt][0][3]));
      float a1 = fmaxf(fmaxf(c[rt][1][0], c[rt][1][1]), fmaxf(c[rt][1][2], c[rt][1][3]));
      pm[rt] = fmaxf(a0, a1);
    }
#pragma unroll
    for (int msk = 16; msk < 64; msk <<= 1)
#pragma unroll
      for (int rt = 0; rt < 2; ++rt) pm[rt] = fmaxf(pm[rt], __shfl_xor(pm[rt], msk, 64));

    // defer-max (T13): only rescale O when max grew by > 8
    int need = (pm[0] > mrow[0] + 8.0f) | (pm[1] > mrow[1] + 8.0f);
    if (__any(need)) {
      float al[2];
#pragma unroll
      for (int rt = 0; rt < 2; ++rt) {
        float mn = fmaxf(mrow[rt], pm[rt]);
        al[rt] = __expf(mrow[rt] - mn);
        mrow[rt] = mn;
        lrow[rt] *= al[rt];
      }
      if (g == 0) { AF[cl] = al[0]; AF[16 + cl] = al[1]; }
#pragma unroll
      for (int rt = 0; rt < 2; ++rt) {
        f32x4 alT = *(const f32x4*)&AF[rt * 16 + g * 4];
#pragma unroll
        for (int nt = 0; nt < 4; ++nt)
#pragma unroll
          for (int r = 0; r < 4; ++r) o[rt][nt][r] *= alT[r];
      }
    }

    // P = exp(S - m); row-sum over k (in-register + 2-step butterfly)
    float rs[2];
#pragma unroll
    for (int rt = 0; rt < 2; ++rt) {
#pragma unroll
      for (int ct = 0; ct < 2; ++ct)
#pragma unroll
        for (int r = 0; r < 4; ++r)
          c[rt][ct][r] = __expf(c[rt][ct][r] - mrow[rt]);
      rs[rt] = (c[rt][0][0] + c[rt][0][1]) + (c[rt][0][2] + c[rt][0][3])
             + (c[rt][1][0] + c[rt][1][1]) + (c[rt][1][2] + c[rt][1][3]);
    }
#pragma unroll
    for (int msk = 16; msk < 64; msk <<= 1)
#pragma unroll
      for (int rt = 0; rt < 2; ++rt) rs[rt] += __shfl_xor(rs[rt], msk, 64);
#pragma unroll
    for (int rt = 0; rt < 2; ++rt) lrow[rt] += rs[rt];

    // P^T -> LDS: 4 contiguous k per lane = one b64 write per (rt,ct)
#pragma unroll
    for (int rt = 0; rt < 2; ++rt)
#pragma unroll
      for (int ct = 0; ct < 2; ++ct) {
        unsigned long long pk =
            (unsigned long long)f2bf(c[rt][ct][0])
          | ((unsigned long long)f2bf(c[rt][ct][1]) << 16)
          | ((unsigned long long)f2bf(c[rt][ct][2]) << 32)
          | ((unsigned long long)f2bf(c[rt][ct][3]) << 48);
        *(unsigned long long*)&P[(rt * 16 + cl) * PSTR + ct * 16 + g * 4] = pk;
      }
    bf16x8 ap[2];
#pragma unroll
    for (int rt = 0; rt < 2; ++rt)
      ap[rt] = load8(&P[(rt * 16 + cl) * PSTR + g * 8]);

    // PV: o += P[32x32] * V[32x64]
#pragma unroll
    for (int rt = 0; rt < 2; ++rt)
#pragma unroll
      for (int nt = 0; nt < 4; ++nt)
        o[rt][nt] = __builtin_amdgcn_mfma_f32_16x16x32_bf16(ap[rt], bv[nt], o[rt][nt], 0, 0, 0);

    // rotate K double-buffer
#pragma unroll
    for (int ct = 0; ct < 2; ++ct)
#pragma unroll
      for (int kh = 0; kh < 2; ++kh) kc[ct][kh] = kn[ct][kh];
  }

  // publish per-wave m,l (q-layout); high wave publishes o fragments
  if (g == 0) {
    Mq[wave][cl] = mrow[0]; Mq[wave][16 + cl] = mrow[1];
    Lq[wave][cl] = lrow[0]; Lq[wave][16 + cl] = lrow[1];
  }
  if (half) {
#pragma unroll
    for (int rt = 0; rt < 2; ++rt)
#pragma unroll
      for (int nt = 0; nt < 4; ++nt)
        *(f32x4*)&Mo[pair][rt * 4 + nt][lane][0] = o[rt][nt];
  }
  __syncthreads();

  if (!half) {
    const int b = bh >> 4, h = bh & 15;
#pragma unroll
    for (int rt = 0; rt < 2; ++rt) {
      // read m,l transposed to o-layout (row = rt*16 + g*4 + r)
      f32x4 m0 = *(const f32x4*)&Mq[wave][rt * 16 + g * 4];
      f32x4 l0 = *(const f32x4*)&Lq[wave][rt * 16 + g * 4];
      f32x4 m1 = *(const f32x4*)&Mq[wave + 1][rt * 16 + g * 4];
      f32x4 l1 = *(const f32x4*)&Lq[wave + 1][rt * 16 + g * 4];
      f32x4 a0, a1, inv;
#pragma unroll
      for (int r = 0; r < 4; ++r) {
        float mm = fmaxf(m0[r], m1[r]);
        a0[r] = __expf(m0[r] - mm);
        a1[r] = __expf(m1[r] - mm);
        inv[r] = 1.0f / (l0[r] * a0[r] + l1[r] * a1[r]);
      }
#pragma unroll
      for (int nt = 0; nt < 4; ++nt) {
        f32x4 o1 = *(const f32x4*)&Mo[pair][rt * 4 + nt][lane][0];
#pragma unroll
        for (int r = 0; r < 4; ++r) {
          int q = qt + rt * 16 + g * 4 + r;
          size_t base = ((size_t)(b * S_LEN + q)) * D_DIM + h * 64;
          Og[base + nt * 16 + cl] = f2bf((o[rt][nt][r] * a0[r] + o1[r] * a1[r]) * inv[r]);
        }
      }
    }
  }
}

extern "C" void kernel_launch(void* const* d_in, const int* in_sizes, int n_in,
                              void* d_out, int out_size, void* d_ws, size_t ws_size,
                              hipStream_t stream) {
  const float* x  = (const float*)d_in[0];
  const float* Wq = (const float*)d_in[1];
  const float* Wk = (const float*)d_in[2];
  const float* Wv = (const float*)d_in[3];
  const float* Wo = (const float*)d_in[4];

  const int M = M_ROWS, D = D_DIM;

  unsigned short* ws  = (unsigned short*)d_ws;
  unsigned short* xb  = ws;                          // M*D
  unsigned short* wqb = xb  + (size_t)M * D;         // D*D
  unsigned short* wkb = wqb + (size_t)D * D;
  unsigned short* wvb = wkb + (size_t)D * D;
  unsigned short* wob = wvb + (size_t)D * D;
  unsigned short* qb  = wob + (size_t)D * D;         // M*D  [B,H,S,64] (scaled)
  unsigned short* kbf = qb  + (size_t)M * D;         // M*D  [B,H,S,64]
  unsigned short* vtb = kbf + (size_t)M * D;         // M*D  [B,H,64,S]
  unsigned short* aob = vtb + (size_t)M * D;         // M*D  [B,S,D]

  // 1) convert inputs to bf16 (single fused launch)
  {
    dim3 gc(M * D / 4 / 256, 5);
    cvt5_kernel<<<gc, 256, 0, stream>>>(x, Wq, Wk, Wv, Wo,
                                        xb, wqb, wkb, wvb, wob,
                                        M * D / 4, D * D / 4);
  }

  // 2) fused QKV projections (Q scaled by 1/8 in epilogue)
  dim3 gq(D / 128, M / 128, 3);
  gemm_bt<<<gq, 256, 0, stream>>>(xb, wqb, wkb, wvb, qb, kbf, vtb, M, D, D, 1);

  // 3) causal flash attention (swapped-QK, split-K, 1024 blocks)
  attn_kernel<<<1024, 256, 0, stream>>>(qb, kbf, vtb, aob);

  // 4) output projection -> fp32 d_out
  dim3 go(D / 128, M / 128, 1);
  gemm_bt<<<go, 256, 0, stream>>>(aob, wob, wob, wob, d_out, d_out, d_out, M, D, D, 0);
}

// Round 5
// 168.974 us; speedup vs baseline: 1.1457x; 1.1457x over previous
//
#include <hip/hip_runtime.h>
#include <hip/hip_bf16.h>

// Problem constants: B=2, S=2048, D=1024, H=16, dk=64
#define S_LEN 2048
#define D_DIM 1024
#define N_HEADS 16
#define M_ROWS 4096  // B*S

typedef __bf16 bf16x8 __attribute__((ext_vector_type(8)));
typedef float f32x4 __attribute__((ext_vector_type(4)));
typedef unsigned short ushortx8 __attribute__((ext_vector_type(8)));

__device__ __forceinline__ unsigned short f2bf(float f) {
  unsigned int u = __builtin_bit_cast(unsigned int, f);
  u += 0x7fffu + ((u >> 16) & 1u);   // RNE
  return (unsigned short)(u >> 16);
}

// v_cvt_pk_bf16_f32: packs 2 f32 -> u32 (lo|hi<<16), RNE. No builtin on gfx950.
__device__ __forceinline__ unsigned int cvtpk(float lo, float hi) {
  unsigned int r;
  asm("v_cvt_pk_bf16_f32 %0, %1, %2" : "=v"(r) : "v"(lo), "v"(hi));
  return r;
}

__device__ __forceinline__ bf16x8 load8(const unsigned short* p) {
  return __builtin_bit_cast(bf16x8, *(const ushortx8*)p);
}

__device__ __forceinline__ void gload16(const unsigned short* g, unsigned short* l) {
  __builtin_amdgcn_global_load_lds((const __attribute__((address_space(1))) void*)g,
                                   (__attribute__((address_space(3))) void*)l,
                                   16, 0, 0);
}

// ---------------- fp32 -> bf16 convert (fused: x + 4 weights) ----------------
__global__ void cvt5_kernel(const float* __restrict__ s0, const float* __restrict__ s1,
                            const float* __restrict__ s2, const float* __restrict__ s3,
                            const float* __restrict__ s4,
                            unsigned short* __restrict__ d0, unsigned short* __restrict__ d1,
                            unsigned short* __restrict__ d2, unsigned short* __restrict__ d3,
                            unsigned short* __restrict__ d4,
                            int n4x, int n4w) {
  const int y = blockIdx.y;
  const float* s = (y == 0) ? s0 : (y == 1) ? s1 : (y == 2) ? s2 : (y == 3) ? s3 : s4;
  unsigned short* d = (y == 0) ? d0 : (y == 1) ? d1 : (y == 2) ? d2 : (y == 3) ? d3 : d4;
  const int n4 = (y == 0) ? n4x : n4w;
  int i = blockIdx.x * blockDim.x + threadIdx.x;
  if (i < n4) {
    float4 f = ((const float4*)s)[i];
    unsigned int u0 = cvtpk(f.x, f.y), u1 = cvtpk(f.z, f.w);
    unsigned long long packed = (unsigned long long)u0 | ((unsigned long long)u1 << 32);
    ((unsigned long long*)d)[i] = packed;
  }
}

// ---------------- bf16 GEMM: C = A[M,K] * B[N,K]^T ----------------
// mode 0: fp32 row-major [M][N] output
// mode 1: bf16 [B,H,S,64] output (Q,K); Q (z==0) pre-scaled by 1/sqrt(dk)
// mode 2: bf16 [B,H,64,S] output (V transposed)
__global__ __launch_bounds__(256) void gemm_bt(
    const unsigned short* __restrict__ A,
    const unsigned short* __restrict__ B0,
    const unsigned short* __restrict__ B1,
    const unsigned short* __restrict__ B2,
    void* __restrict__ C0, void* __restrict__ C1, void* __restrict__ C2,
    int M, int N, int K, int modesel)
{
  __shared__ __align__(16) unsigned short At[128 * 64];
  __shared__ __align__(16) unsigned short Bt[128 * 64];

  const int z = blockIdx.z;
  const unsigned short* Bp = (z == 0) ? B0 : (z == 1) ? B1 : B2;
  void* Cp = (z == 0) ? C0 : (z == 1) ? C1 : C2;
  const int mode = (modesel == 0) ? 0 : ((z == 2) ? 2 : 1);
  const float escale = (modesel == 1 && z == 0) ? 0.125f : 1.0f;

  const int tid = threadIdx.x;
  const int lane = tid & 63, wave = tid >> 6;
  const int bm = blockIdx.y * 128, bn = blockIdx.x * 128;
  const int wr = wave >> 1, wc = wave & 1;           // 2x2 wave grid, 64x64 each
  const int cl = lane & 15, g = lane >> 4;
  // staging: chunks of 512 elems (8 rows x 64 elems); pre-swizzled global slot
  const int ci = lane >> 3, si = lane & 7;
  const int sg = si ^ (ci & 7);

  f32x4 acc[4][4] = {};

  for (int kb = 0; kb < K; kb += 64) {
    __syncthreads();
#pragma unroll
    for (int cc = 0; cc < 4; ++cc) {
      int chunk = wave * 4 + cc;
      int row = chunk * 8 + ci;
      gload16(A  + (size_t)(bm + row) * K + kb + sg * 8, &At[chunk * 512]);
      gload16(Bp + (size_t)(bn + row) * K + kb + sg * 8, &Bt[chunk * 512]);
    }
    __syncthreads();
#pragma unroll
    for (int kc = 0; kc < 2; ++kc) {
      bf16x8 af[4], bfr[4];
#pragma unroll
      for (int mi = 0; mi < 4; ++mi) {
        int row = wr * 64 + mi * 16 + cl;
        int slot = (kc * 4 + g) ^ (row & 7);
        af[mi] = load8(&At[row * 64 + slot * 8]);
      }
#pragma unroll
      for (int ni = 0; ni < 4; ++ni) {
        int row = wc * 64 + ni * 16 + cl;
        int slot = (kc * 4 + g) ^ (row & 7);
        bfr[ni] = load8(&Bt[row * 64 + slot * 8]);
      }
#pragma unroll
      for (int mi = 0; mi < 4; ++mi)
#pragma unroll
        for (int ni = 0; ni < 4; ++ni)
          acc[mi][ni] = __builtin_amdgcn_mfma_f32_16x16x32_bf16(af[mi], bfr[ni], acc[mi][ni], 0, 0, 0);
    }
  }

  // epilogue: C row = (lane>>4)*4 + reg, col = lane&15
  const int r0 = g * 4;
#pragma unroll
  for (int mi = 0; mi < 4; ++mi) {
#pragma unroll
    for (int ni = 0; ni < 4; ++ni) {
      int mg = bm + wr * 64 + mi * 16 + r0;
      int ng = bn + wc * 64 + ni * 16 + cl;
#pragma unroll
      for (int r = 0; r < 4; ++r) {
        float v = acc[mi][ni][r] * escale;
        int m = mg + r;
        if (mode == 0) {
          ((float*)Cp)[(size_t)m * N + ng] = v;
        } else {
          int b = m >> 11, s = m & 2047;        // S=2048
          int h = ng >> 6, d = ng & 63;         // dk=64
          unsigned short* o = (unsigned short*)Cp;
          if (mode == 1) o[((size_t)(b * N_HEADS + h) * S_LEN + s) * 64 + d] = f2bf(v);
          else           o[((size_t)(b * N_HEADS + h) * 64 + d) * S_LEN + s] = f2bf(v);
        }
      }
    }
  }
}

// ---------------- causal flash attention: swapped-QK + split-K ---------------
// Q,K: [BH][S][64] bf16 (Q pre-scaled); Vt: [BH][64][S] bf16; out: [B][S][H*64] bf16
// 1024 blocks x 4 waves. Block owns 64 q-rows (2 pairs of waves). Within a pair,
// wave half=0 takes the low half of the key range (no mask), half=1 takes the
// high half (owns the diagonal). Partials merged in LDS after one barrier.
// NOTE: no min-waves __launch_bounds__ hint — forcing 4 waves/EU squeezed VGPR
// to 64 and spilled ~8MB/dispatch to scratch (round-4 WRITE_SIZE doubled).
#define PSTR 40   // padded P row stride (elems)

__global__ __launch_bounds__(256) void attn_kernel(
    const unsigned short* __restrict__ Qg,
    const unsigned short* __restrict__ Kg,
    const unsigned short* __restrict__ Vtg,
    unsigned short* __restrict__ Og)
{
  __shared__ __align__(16) unsigned short Pt[4][32 * PSTR];  // per-wave P buffer
  __shared__ __align__(16) float Af[4][32];                  // per-wave alpha transpose
  __shared__ __align__(16) float Mo[2][8][64][4];            // half=1 o frags [pair][rt*4+nt][lane]
  __shared__ __align__(16) float Mq[4][32], Lq[4][32];       // per-wave m,l (q-layout)

  const int tid = threadIdx.x;
  const int lane = tid & 63, wave = tid >> 6;
  const int cl = lane & 15, g = lane >> 4;
  const int pair = wave >> 1, half = wave & 1;

  // XCD-contiguous swizzle; heavy q-chunks first within each bh
  const int wg = (blockIdx.x & 7) * 128 + (blockIdx.x >> 3);
  const int bh = wg >> 5;               // 32 (b,h) pairs, 4 per XCD
  const int qc = 31 - (wg & 31);        // 64-row chunks, descending work order
  const int qt = qc * 64 + pair * 32;   // this pair's 32 q-rows

  const size_t qkb = (size_t)bh * S_LEN;
  unsigned short* P = &Pt[wave][0];
  float* AF = &Af[wave][0];

  const int nkb = qt / 32 + 1;
  const int kmid = nkb >> 1;
  const int kb0 = half ? kmid : 0;
  const int kb1 = half ? nkb : kmid;

  // Q fragments in registers (already scaled by 1/8)
  bf16x8 aq[2][2];
#pragma unroll
  for (int rt = 0; rt < 2; ++rt)
#pragma unroll
    for (int kh = 0; kh < 2; ++kh)
      aq[rt][kh] = load8(Qg + (qkb + qt + rt * 16 + cl) * 64 + kh * 32 + g * 8);

  f32x4 o[2][4] = {};
  float mrow[2] = {-1e30f, -1e30f};
  float lrow[2] = {0.f, 0.f};

  // K fragment double-buffer
  bf16x8 kc[2][2], kn[2][2];
#pragma unroll
  for (int ct = 0; ct < 2; ++ct)
#pragma unroll
    for (int kh = 0; kh < 2; ++kh)
      kc[ct][kh] = load8(Kg + (qkb + kb0 * 32 + ct * 16 + cl) * 64 + kh * 32 + g * 8);

  for (int kb = kb0; kb < kb1; ++kb) {
    const int kbase = kb * 32;

    // V^T fragments for THIS block (used far below -> latency hidden)
    bf16x8 bv[4];
#pragma unroll
    for (int nt = 0; nt < 4; ++nt)
      bv[nt] = load8(Vtg + ((size_t)bh * 64 + nt * 16 + cl) * S_LEN + kbase + g * 8);
    // prefetch K for next block
    {
      int nb = (kb + 1 < kb1) ? kbase + 32 : kbase;
#pragma unroll
      for (int ct = 0; ct < 2; ++ct)
#pragma unroll
        for (int kh = 0; kh < 2; ++kh)
          kn[ct][kh] = load8(Kg + (qkb + nb + ct * 16 + cl) * 64 + kh * 32 + g * 8);
    }

    // swapped scores: Ct[k][q] = K·Q^T; lane holds q=rt*16+cl, k=ct*16+g*4+r
    f32x4 c[2][2] = {};
#pragma unroll
    for (int rt = 0; rt < 2; ++rt)
#pragma unroll
      for (int ct = 0; ct < 2; ++ct) {
        c[rt][ct] = __builtin_amdgcn_mfma_f32_16x16x32_bf16(kc[ct][0], aq[rt][0], c[rt][ct], 0, 0, 0);
        c[rt][ct] = __builtin_amdgcn_mfma_f32_16x16x32_bf16(kc[ct][1], aq[rt][1], c[rt][ct], 0, 0, 0);
      }

    if (half && kb == nkb - 1) {   // diagonal block (only the high wave sees it)
#pragma unroll
      for (int rt = 0; rt < 2; ++rt) {
        int q = qt + rt * 16 + cl;
#pragma unroll
        for (int ct = 0; ct < 2; ++ct) {
          int k0 = kbase + ct * 16 + g * 4;
#pragma unroll
          for (int r = 0; r < 4; ++r)
            if (k0 + r > q) c[rt][ct][r] = -1e30f;
        }
      }
    }

    // row max over k: in-register + 2-step butterfly over g-groups
    float pm[2];
#pragma unroll
    for (int rt = 0; rt < 2; ++rt) {
      float a0 = fmaxf(fmaxf(c[rt][0][0], c[rt][0][1]), fmaxf(c[rt][0][2], c[rt][0][3]));
      float a1 = fmaxf(fmaxf(c[rt][1][0], c[rt][1][1]), fmaxf(c[rt][1][2], c[rt][1][3]));
      pm[rt] = fmaxf(a0, a1);
    }
#pragma unroll
    for (int msk = 16; msk < 64; msk <<= 1)
#pragma unroll
      for (int rt = 0; rt < 2; ++rt) pm[rt] = fmaxf(pm[rt], __shfl_xor(pm[rt], msk, 64));

    // defer-max (T13): only rescale O when max grew by > 8
    int need = (pm[0] > mrow[0] + 8.0f) | (pm[1] > mrow[1] + 8.0f);
    if (__any(need)) {
      float al[2];
#pragma unroll
      for (int rt = 0; rt < 2; ++rt) {
        float mn = fmaxf(mrow[rt], pm[rt]);
        al[rt] = __expf(mrow[rt] - mn);
        mrow[rt] = mn;
        lrow[rt] *= al[rt];
      }
      if (g == 0) { AF[cl] = al[0]; AF[16 + cl] = al[1]; }
#pragma unroll
      for (int rt = 0; rt < 2; ++rt) {
        f32x4 alT = *(const f32x4*)&AF[rt * 16 + g * 4];
#pragma unroll
        for (int nt = 0; nt < 4; ++nt)
#pragma unroll
          for (int r = 0; r < 4; ++r) o[rt][nt][r] *= alT[r];
      }
    }

    // P = exp(S - m); row-sum over k (in-register + 2-step butterfly)
    float rs[2];
#pragma unroll
    for (int rt = 0; rt < 2; ++rt) {
#pragma unroll
      for (int ct = 0; ct < 2; ++ct)
#pragma unroll
        for (int r = 0; r < 4; ++r)
          c[rt][ct][r] = __expf(c[rt][ct][r] - mrow[rt]);
      rs[rt] = (c[rt][0][0] + c[rt][0][1]) + (c[rt][0][2] + c[rt][0][3])
             + (c[rt][1][0] + c[rt][1][1]) + (c[rt][1][2] + c[rt][1][3]);
    }
#pragma unroll
    for (int msk = 16; msk < 64; msk <<= 1)
#pragma unroll
      for (int rt = 0; rt < 2; ++rt) rs[rt] += __shfl_xor(rs[rt], msk, 64);
#pragma unroll
    for (int rt = 0; rt < 2; ++rt) lrow[rt] += rs[rt];

    // P^T -> LDS: cvt_pk packs 4 contiguous k into u64 (one b64 write per rt,ct)
#pragma unroll
    for (int rt = 0; rt < 2; ++rt)
#pragma unroll
      for (int ct = 0; ct < 2; ++ct) {
        unsigned int u0 = cvtpk(c[rt][ct][0], c[rt][ct][1]);
        unsigned int u1 = cvtpk(c[rt][ct][2], c[rt][ct][3]);
        unsigned long long pk = (unsigned long long)u0 | ((unsigned long long)u1 << 32);
        *(unsigned long long*)&P[(rt * 16 + cl) * PSTR + ct * 16 + g * 4] = pk;
      }
    bf16x8 ap[2];
#pragma unroll
    for (int rt = 0; rt < 2; ++rt)
      ap[rt] = load8(&P[(rt * 16 + cl) * PSTR + g * 8]);

    // PV: o += P[32x32] * V[32x64]
#pragma unroll
    for (int rt = 0; rt < 2; ++rt)
#pragma unroll
      for (int nt = 0; nt < 4; ++nt)
        o[rt][nt] = __builtin_amdgcn_mfma_f32_16x16x32_bf16(ap[rt], bv[nt], o[rt][nt], 0, 0, 0);

    // rotate K double-buffer
#pragma unroll
    for (int ct = 0; ct < 2; ++ct)
#pragma unroll
      for (int kh = 0; kh < 2; ++kh) kc[ct][kh] = kn[ct][kh];
  }

  // publish per-wave m,l (q-layout); high wave publishes o fragments
  if (g == 0) {
    Mq[wave][cl] = mrow[0]; Mq[wave][16 + cl] = mrow[1];
    Lq[wave][cl] = lrow[0]; Lq[wave][16 + cl] = lrow[1];
  }
  if (half) {
#pragma unroll
    for (int rt = 0; rt < 2; ++rt)
#pragma unroll
      for (int nt = 0; nt < 4; ++nt)
        *(f32x4*)&Mo[pair][rt * 4 + nt][lane][0] = o[rt][nt];
  }
  __syncthreads();

  if (!half) {
    const int b = bh >> 4, h = bh & 15;
#pragma unroll
    for (int rt = 0; rt < 2; ++rt) {
      // read m,l transposed to o-layout (row = rt*16 + g*4 + r)
      f32x4 m0 = *(const f32x4*)&Mq[wave][rt * 16 + g * 4];
      f32x4 l0 = *(const f32x4*)&Lq[wave][rt * 16 + g * 4];
      f32x4 m1 = *(const f32x4*)&Mq[wave + 1][rt * 16 + g * 4];
      f32x4 l1 = *(const f32x4*)&Lq[wave + 1][rt * 16 + g * 4];
      f32x4 a0, a1, inv;
#pragma unroll
      for (int r = 0; r < 4; ++r) {
        float mm = fmaxf(m0[r], m1[r]);
        a0[r] = __expf(m0[r] - mm);
        a1[r] = __expf(m1[r] - mm);
        inv[r] = 1.0f / (l0[r] * a0[r] + l1[r] * a1[r]);
      }
#pragma unroll
      for (int nt = 0; nt < 4; ++nt) {
        f32x4 o1 = *(const f32x4*)&Mo[pair][rt * 4 + nt][lane][0];
#pragma unroll
        for (int r = 0; r < 4; ++r) {
          int q = qt + rt * 16 + g * 4 + r;
          size_t base = ((size_t)(b * S_LEN + q)) * D_DIM + h * 64;
          Og[base + nt * 16 + cl] = f2bf((o[rt][nt][r] * a0[r] + o1[r] * a1[r]) * inv[r]);
        }
      }
    }
  }
}

extern "C" void kernel_launch(void* const* d_in, const int* in_sizes, int n_in,
                              void* d_out, int out_size, void* d_ws, size_t ws_size,
                              hipStream_t stream) {
  const float* x  = (const float*)d_in[0];
  const float* Wq = (const float*)d_in[1];
  const float* Wk = (const float*)d_in[2];
  const float* Wv = (const float*)d_in[3];
  const float* Wo = (const float*)d_in[4];

  const int M = M_ROWS, D = D_DIM;

  unsigned short* ws  = (unsigned short*)d_ws;
  unsigned short* xb  = ws;                          // M*D
  unsigned short* wqb = xb  + (size_t)M * D;         // D*D
  unsigned short* wkb = wqb + (size_t)D * D;
  unsigned short* wvb = wkb + (size_t)D * D;
  unsigned short* wob = wvb + (size_t)D * D;
  unsigned short* qb  = wob + (size_t)D * D;         // M*D  [B,H,S,64] (scaled)
  unsigned short* kbf = qb  + (size_t)M * D;         // M*D  [B,H,S,64]
  unsigned short* vtb = kbf + (size_t)M * D;         // M*D  [B,H,64,S]
  unsigned short* aob = vtb + (size_t)M * D;         // M*D  [B,S,D]

  // 1) convert inputs to bf16 (single fused launch)
  {
    dim3 gc(M * D / 4 / 256, 5);
    cvt5_kernel<<<gc, 256, 0, stream>>>(x, Wq, Wk, Wv, Wo,
                                        xb, wqb, wkb, wvb, wob,
                                        M * D / 4, D * D / 4);
  }

  // 2) fused QKV projections (Q scaled by 1/8 in epilogue)
  dim3 gq(D / 128, M / 128, 3);
  gemm_bt<<<gq, 256, 0, stream>>>(xb, wqb, wkb, wvb, qb, kbf, vtb, M, D, D, 1);

  // 3) causal flash attention (swapped-QK, split-K, 1024 blocks)
  attn_kernel<<<1024, 256, 0, stream>>>(qb, kbf, vtb, aob);

  // 4) output projection -> fp32 d_out
  dim3 go(D / 128, M / 128, 1);
  gemm_bt<<<go, 256, 0, stream>>>(aob, wob, wob, wob, d_out, d_out, d_out, M, D, D, 0);
}

// Round 6
// 146.671 us; speedup vs baseline: 1.3199x; 1.1521x over previous
//
#include <hip/hip_runtime.h>
#include <hip/hip_bf16.h>

// Problem constants: B=2, S=2048, D=1024, H=16, dk=64
#define S_LEN 2048
#define D_DIM 1024
#define N_HEADS 16
#define M_ROWS 4096  // B*S

typedef __bf16 bf16x8 __attribute__((ext_vector_type(8)));
typedef float f32x4 __attribute__((ext_vector_type(4)));
typedef unsigned short ushortx8 __attribute__((ext_vector_type(8)));

__device__ __forceinline__ unsigned short f2bf(float f) {
  unsigned int u = __builtin_bit_cast(unsigned int, f);
  u += 0x7fffu + ((u >> 16) & 1u);   // RNE
  return (unsigned short)(u >> 16);
}

// v_cvt_pk_bf16_f32: packs 2 f32 -> u32 (lo|hi<<16), RNE. No builtin on gfx950.
__device__ __forceinline__ unsigned int cvtpk(float lo, float hi) {
  unsigned int r;
  asm("v_cvt_pk_bf16_f32 %0, %1, %2" : "=v"(r) : "v"(lo), "v"(hi));
  return r;
}

__device__ __forceinline__ bf16x8 load8(const unsigned short* p) {
  return __builtin_bit_cast(bf16x8, *(const ushortx8*)p);
}

__device__ __forceinline__ void gload16(const unsigned short* g, unsigned short* l) {
  __builtin_amdgcn_global_load_lds((const __attribute__((address_space(1))) void*)g,
                                   (__attribute__((address_space(3))) void*)l,
                                   16, 0, 0);
}

// ---------------- fp32 -> bf16 convert (fused: x + 4 weights) ----------------
__global__ void cvt5_kernel(const float* __restrict__ s0, const float* __restrict__ s1,
                            const float* __restrict__ s2, const float* __restrict__ s3,
                            const float* __restrict__ s4,
                            unsigned short* __restrict__ d0, unsigned short* __restrict__ d1,
                            unsigned short* __restrict__ d2, unsigned short* __restrict__ d3,
                            unsigned short* __restrict__ d4,
                            int n4x, int n4w) {
  const int y = blockIdx.y;
  const float* s = (y == 0) ? s0 : (y == 1) ? s1 : (y == 2) ? s2 : (y == 3) ? s3 : s4;
  unsigned short* d = (y == 0) ? d0 : (y == 1) ? d1 : (y == 2) ? d2 : (y == 3) ? d3 : d4;
  const int n4 = (y == 0) ? n4x : n4w;
  int i = blockIdx.x * blockDim.x + threadIdx.x;
  if (i < n4) {
    float4 f = ((const float4*)s)[i];
    unsigned int u0 = cvtpk(f.x, f.y), u1 = cvtpk(f.z, f.w);
    unsigned long long packed = (unsigned long long)u0 | ((unsigned long long)u1 << 32);
    ((unsigned long long*)d)[i] = packed;
  }
}

// ---------------- bf16 GEMM: C = A[M,K] * B[N,K]^T ----------------
// mode 0: fp32 row-major [M][N] output
// mode 1: bf16 [B,H,S,64] output (Q,K); Q (z==0) pre-scaled by 1/sqrt(dk)
// mode 2: bf16 [B,H,64,S] output (V transposed)
__global__ __launch_bounds__(256) void gemm_bt(
    const unsigned short* __restrict__ A,
    const unsigned short* __restrict__ B0,
    const unsigned short* __restrict__ B1,
    const unsigned short* __restrict__ B2,
    void* __restrict__ C0, void* __restrict__ C1, void* __restrict__ C2,
    int M, int N, int K, int modesel)
{
  __shared__ __align__(16) unsigned short At[128 * 64];
  __shared__ __align__(16) unsigned short Bt[128 * 64];

  const int z = blockIdx.z;
  const unsigned short* Bp = (z == 0) ? B0 : (z == 1) ? B1 : B2;
  void* Cp = (z == 0) ? C0 : (z == 1) ? C1 : C2;
  const int mode = (modesel == 0) ? 0 : ((z == 2) ? 2 : 1);
  const float escale = (modesel == 1 && z == 0) ? 0.125f : 1.0f;

  const int tid = threadIdx.x;
  const int lane = tid & 63, wave = tid >> 6;
  const int bm = blockIdx.y * 128, bn = blockIdx.x * 128;
  const int wr = wave >> 1, wc = wave & 1;           // 2x2 wave grid, 64x64 each
  const int cl = lane & 15, g = lane >> 4;
  // staging: chunks of 512 elems (8 rows x 64 elems); pre-swizzled global slot
  const int ci = lane >> 3, si = lane & 7;
  const int sg = si ^ (ci & 7);

  f32x4 acc[4][4] = {};

  for (int kb = 0; kb < K; kb += 64) {
    __syncthreads();
#pragma unroll
    for (int cc = 0; cc < 4; ++cc) {
      int chunk = wave * 4 + cc;
      int row = chunk * 8 + ci;
      gload16(A  + (size_t)(bm + row) * K + kb + sg * 8, &At[chunk * 512]);
      gload16(Bp + (size_t)(bn + row) * K + kb + sg * 8, &Bt[chunk * 512]);
    }
    __syncthreads();
#pragma unroll
    for (int kc = 0; kc < 2; ++kc) {
      bf16x8 af[4], bfr[4];
#pragma unroll
      for (int mi = 0; mi < 4; ++mi) {
        int row = wr * 64 + mi * 16 + cl;
        int slot = (kc * 4 + g) ^ (row & 7);
        af[mi] = load8(&At[row * 64 + slot * 8]);
      }
#pragma unroll
      for (int ni = 0; ni < 4; ++ni) {
        int row = wc * 64 + ni * 16 + cl;
        int slot = (kc * 4 + g) ^ (row & 7);
        bfr[ni] = load8(&Bt[row * 64 + slot * 8]);
      }
#pragma unroll
      for (int mi = 0; mi < 4; ++mi)
#pragma unroll
        for (int ni = 0; ni < 4; ++ni)
          acc[mi][ni] = __builtin_amdgcn_mfma_f32_16x16x32_bf16(af[mi], bfr[ni], acc[mi][ni], 0, 0, 0);
    }
  }

  // epilogue: C row = (lane>>4)*4 + reg, col = lane&15
  const int r0 = g * 4;
#pragma unroll
  for (int mi = 0; mi < 4; ++mi) {
#pragma unroll
    for (int ni = 0; ni < 4; ++ni) {
      int mg = bm + wr * 64 + mi * 16 + r0;
      int ng = bn + wc * 64 + ni * 16 + cl;
#pragma unroll
      for (int r = 0; r < 4; ++r) {
        float v = acc[mi][ni][r] * escale;
        int m = mg + r;
        if (mode == 0) {
          ((float*)Cp)[(size_t)m * N + ng] = v;
        } else {
          int b = m >> 11, s = m & 2047;        // S=2048
          int h = ng >> 6, d = ng & 63;         // dk=64
          unsigned short* o = (unsigned short*)Cp;
          if (mode == 1) o[((size_t)(b * N_HEADS + h) * S_LEN + s) * 64 + d] = f2bf(v);
          else           o[((size_t)(b * N_HEADS + h) * 64 + d) * S_LEN + s] = f2bf(v);
        }
      }
    }
  }
}

// ------------- causal flash attention: swapped-QK + 4-way split-K ------------
// Q,K: [BH][S][64] bf16 (Q pre-scaled); Vt: [BH][64][S] bf16; out: [B][S][H*64] bf16
// 2048 blocks x 4 waves. Block owns ONE 32-q-row tile; wave w handles key-block
// range [w*nkb/4, (w+1)*nkb/4) -> longest chain nkb/4 <= 16. Partial (m, l, o)
// merged in LDS after one barrier (exact). l kept as per-lane partial; its
// cross-lane butterfly is deferred to the single end-of-loop reduction.
#define PSTR 40   // padded P row stride (elems)

__global__ __launch_bounds__(256) void attn_kernel(
    const unsigned short* __restrict__ Qg,
    const unsigned short* __restrict__ Kg,
    const unsigned short* __restrict__ Vtg,
    unsigned short* __restrict__ Og)
{
  __shared__ __align__(16) unsigned short Pt[4][32 * PSTR];  // per-wave P buffer
  __shared__ __align__(16) float Af[4][32];                  // per-wave alpha transpose
  __shared__ __align__(16) float Mo[3][8][64][4];            // waves 1-3 o frags
  __shared__ __align__(16) float Mq[4][32], Lq[4][32];       // per-wave m,l (q-layout)

  const int tid = threadIdx.x;
  const int lane = tid & 63, wave = tid >> 6;
  const int cl = lane & 15, g = lane >> 4;

  // XCD-contiguous swizzle; 4 bh per XCD; heavy q-tiles first
  const int L = blockIdx.x >> 3;
  const int bh = (blockIdx.x & 7) * 4 + (L & 3);   // 32 (b,h) pairs
  const int qtile = 63 - (L >> 2);                 // descending work order
  const int qt = qtile * 32;

  const size_t qkb = (size_t)bh * S_LEN;
  unsigned short* P = &Pt[wave][0];
  float* AF = &Af[wave][0];

  const int nkb = qtile + 1;
  const int kb0 = (nkb * wave) >> 2;
  const int kb1 = (nkb * (wave + 1)) >> 2;

  // Q fragments in registers (already scaled by 1/8); all 4 waves same tile
  bf16x8 aq[2][2];
#pragma unroll
  for (int rt = 0; rt < 2; ++rt)
#pragma unroll
    for (int kh = 0; kh < 2; ++kh)
      aq[rt][kh] = load8(Qg + (qkb + qt + rt * 16 + cl) * 64 + kh * 32 + g * 8);

  f32x4 o[2][4] = {};
  float mrow[2] = {-1e30f, -1e30f};
  float lpart[2] = {0.f, 0.f};    // per-lane partial row-sum (reduced at end)

  // K fragment double-buffer
  bf16x8 kc[2][2], kn[2][2];
#pragma unroll
  for (int ct = 0; ct < 2; ++ct)
#pragma unroll
    for (int kh = 0; kh < 2; ++kh)
      kc[ct][kh] = load8(Kg + (qkb + kb0 * 32 + ct * 16 + cl) * 64 + kh * 32 + g * 8);

  for (int kb = kb0; kb < kb1; ++kb) {
    const int kbase = kb * 32;

    // V^T fragments for THIS block (used far below -> latency hidden)
    bf16x8 bv[4];
#pragma unroll
    for (int nt = 0; nt < 4; ++nt)
      bv[nt] = load8(Vtg + ((size_t)bh * 64 + nt * 16 + cl) * S_LEN + kbase + g * 8);
    // prefetch K for next block
    {
      int nb = (kb + 1 < kb1) ? kbase + 32 : kbase;
#pragma unroll
      for (int ct = 0; ct < 2; ++ct)
#pragma unroll
        for (int kh = 0; kh < 2; ++kh)
          kn[ct][kh] = load8(Kg + (qkb + nb + ct * 16 + cl) * 64 + kh * 32 + g * 8);
    }

    // swapped scores: Ct[k][q] = K·Q^T; lane holds q=rt*16+cl, k=ct*16+g*4+r
    f32x4 c[2][2] = {};
#pragma unroll
    for (int rt = 0; rt < 2; ++rt)
#pragma unroll
      for (int ct = 0; ct < 2; ++ct) {
        c[rt][ct] = __builtin_amdgcn_mfma_f32_16x16x32_bf16(kc[ct][0], aq[rt][0], c[rt][ct], 0, 0, 0);
        c[rt][ct] = __builtin_amdgcn_mfma_f32_16x16x32_bf16(kc[ct][1], aq[rt][1], c[rt][ct], 0, 0, 0);
      }

    if (kb == nkb - 1) {   // diagonal block (only wave 3 reaches it)
#pragma unroll
      for (int rt = 0; rt < 2; ++rt) {
        int q = qt + rt * 16 + cl;
#pragma unroll
        for (int ct = 0; ct < 2; ++ct) {
          int k0 = kbase + ct * 16 + g * 4;
#pragma unroll
          for (int r = 0; r < 4; ++r)
            if (k0 + r > q) c[rt][ct][r] = -1e30f;
        }
      }
    }

    // row max over k: in-register + 2-step butterfly over g-groups
    float pm[2];
#pragma unroll
    for (int rt = 0; rt < 2; ++rt) {
      float a0 = fmaxf(fmaxf(c[rt][0][0], c[rt][0][1]), fmaxf(c[rt][0][2], c[rt][0][3]));
      float a1 = fmaxf(fmaxf(c[rt][1][0], c[rt][1][1]), fmaxf(c[rt][1][2], c[rt][1][3]));
      pm[rt] = fmaxf(a0, a1);
    }
#pragma unroll
    for (int msk = 16; msk < 64; msk <<= 1)
#pragma unroll
      for (int rt = 0; rt < 2; ++rt) pm[rt] = fmaxf(pm[rt], __shfl_xor(pm[rt], msk, 64));

    // defer-max (T13): only rescale O when max grew by > 8
    int need = (pm[0] > mrow[0] + 8.0f) | (pm[1] > mrow[1] + 8.0f);
    if (__any(need)) {
      float al[2];
#pragma unroll
      for (int rt = 0; rt < 2; ++rt) {
        float mn = fmaxf(mrow[rt], pm[rt]);
        al[rt] = __expf(mrow[rt] - mn);
        mrow[rt] = mn;
        lpart[rt] *= al[rt];
      }
      if (g == 0) { AF[cl] = al[0]; AF[16 + cl] = al[1]; }
#pragma unroll
      for (int rt = 0; rt < 2; ++rt) {
        f32x4 alT = *(const f32x4*)&AF[rt * 16 + g * 4];
#pragma unroll
        for (int nt = 0; nt < 4; ++nt)
#pragma unroll
          for (int r = 0; r < 4; ++r) o[rt][nt][r] *= alT[r];
      }
    }

    // P = exp(S - m); accumulate per-lane partial row-sum (no butterfly here)
#pragma unroll
    for (int rt = 0; rt < 2; ++rt) {
#pragma unroll
      for (int ct = 0; ct < 2; ++ct)
#pragma unroll
        for (int r = 0; r < 4; ++r)
          c[rt][ct][r] = __expf(c[rt][ct][r] - mrow[rt]);
      lpart[rt] += (c[rt][0][0] + c[rt][0][1]) + (c[rt][0][2] + c[rt][0][3])
                 + (c[rt][1][0] + c[rt][1][1]) + (c[rt][1][2] + c[rt][1][3]);
    }

    // P^T -> LDS: cvt_pk packs 4 contiguous k into u64 (one b64 write per rt,ct)
#pragma unroll
    for (int rt = 0; rt < 2; ++rt)
#pragma unroll
      for (int ct = 0; ct < 2; ++ct) {
        unsigned int u0 = cvtpk(c[rt][ct][0], c[rt][ct][1]);
        unsigned int u1 = cvtpk(c[rt][ct][2], c[rt][ct][3]);
        unsigned long long pk = (unsigned long long)u0 | ((unsigned long long)u1 << 32);
        *(unsigned long long*)&P[(rt * 16 + cl) * PSTR + ct * 16 + g * 4] = pk;
      }
    bf16x8 ap[2];
#pragma unroll
    for (int rt = 0; rt < 2; ++rt)
      ap[rt] = load8(&P[(rt * 16 + cl) * PSTR + g * 8]);

    // PV: o += P[32x32] * V[32x64]
#pragma unroll
    for (int rt = 0; rt < 2; ++rt)
#pragma unroll
      for (int nt = 0; nt < 4; ++nt)
        o[rt][nt] = __builtin_amdgcn_mfma_f32_16x16x32_bf16(ap[rt], bv[nt], o[rt][nt], 0, 0, 0);

    // rotate K double-buffer
#pragma unroll
    for (int ct = 0; ct < 2; ++ct)
#pragma unroll
      for (int kh = 0; kh < 2; ++kh) kc[ct][kh] = kn[ct][kh];
  }

  // one deferred l butterfly (cross-g), then publish partials
  float lfull[2] = {lpart[0], lpart[1]};
#pragma unroll
  for (int msk = 16; msk < 64; msk <<= 1)
#pragma unroll
    for (int rt = 0; rt < 2; ++rt) lfull[rt] += __shfl_xor(lfull[rt], msk, 64);

  if (g == 0) {
    Mq[wave][cl] = mrow[0]; Mq[wave][16 + cl] = mrow[1];
    Lq[wave][cl] = lfull[0]; Lq[wave][16 + cl] = lfull[1];
  }
  if (wave) {
#pragma unroll
    for (int rt = 0; rt < 2; ++rt)
#pragma unroll
      for (int nt = 0; nt < 4; ++nt)
        *(f32x4*)&Mo[wave - 1][rt * 4 + nt][lane][0] = o[rt][nt];
  }
  __syncthreads();

  if (wave == 0) {
    const int b = bh >> 4, h = bh & 15;
#pragma unroll
    for (int rt = 0; rt < 2; ++rt) {
      // m,l transposed to o-layout (row = rt*16 + g*4 + r)
      f32x4 mw[4], lw[4];
#pragma unroll
      for (int w = 0; w < 4; ++w) {
        mw[w] = *(const f32x4*)&Mq[w][rt * 16 + g * 4];
        lw[w] = *(const f32x4*)&Lq[w][rt * 16 + g * 4];
      }
      f32x4 aw[4], inv;
#pragma unroll
      for (int r = 0; r < 4; ++r) {
        float mm = fmaxf(fmaxf(mw[0][r], mw[1][r]), fmaxf(mw[2][r], mw[3][r]));
        float lsum = 0.f;
#pragma unroll
        for (int w = 0; w < 4; ++w) {
          aw[w][r] = __expf(mw[w][r] - mm);
          lsum += lw[w][r] * aw[w][r];
        }
        inv[r] = 1.0f / lsum;
      }
#pragma unroll
      for (int nt = 0; nt < 4; ++nt) {
        f32x4 of;
#pragma unroll
        for (int r = 0; r < 4; ++r) of[r] = o[rt][nt][r] * aw[0][r];
#pragma unroll
        for (int w = 1; w < 4; ++w) {
          f32x4 ow = *(const f32x4*)&Mo[w - 1][rt * 4 + nt][lane][0];
#pragma unroll
          for (int r = 0; r < 4; ++r) of[r] += ow[r] * aw[w][r];
        }
#pragma unroll
        for (int r = 0; r < 4; ++r) {
          int q = qt + rt * 16 + g * 4 + r;
          size_t base = ((size_t)(b * S_LEN + q)) * D_DIM + h * 64;
          Og[base + nt * 16 + cl] = f2bf(of[r] * inv[r]);
        }
      }
    }
  }
}

extern "C" void kernel_launch(void* const* d_in, const int* in_sizes, int n_in,
                              void* d_out, int out_size, void* d_ws, size_t ws_size,
                              hipStream_t stream) {
  const float* x  = (const float*)d_in[0];
  const float* Wq = (const float*)d_in[1];
  const float* Wk = (const float*)d_in[2];
  const float* Wv = (const float*)d_in[3];
  const float* Wo = (const float*)d_in[4];

  const int M = M_ROWS, D = D_DIM;

  unsigned short* ws  = (unsigned short*)d_ws;
  unsigned short* xb  = ws;                          // M*D
  unsigned short* wqb = xb  + (size_t)M * D;         // D*D
  unsigned short* wkb = wqb + (size_t)D * D;
  unsigned short* wvb = wkb + (size_t)D * D;
  unsigned short* wob = wvb + (size_t)D * D;
  unsigned short* qb  = wob + (size_t)D * D;         // M*D  [B,H,S,64] (scaled)
  unsigned short* kbf = qb  + (size_t)M * D;         // M*D  [B,H,S,64]
  unsigned short* vtb = kbf + (size_t)M * D;         // M*D  [B,H,64,S]
  unsigned short* aob = vtb + (size_t)M * D;         // M*D  [B,S,D]

  // 1) convert inputs to bf16 (single fused launch)
  {
    dim3 gc(M * D / 4 / 256, 5);
    cvt5_kernel<<<gc, 256, 0, stream>>>(x, Wq, Wk, Wv, Wo,
                                        xb, wqb, wkb, wvb, wob,
                                        M * D / 4, D * D / 4);
  }

  // 2) fused QKV projections (Q scaled by 1/8 in epilogue)
  dim3 gq(D / 128, M / 128, 3);
  gemm_bt<<<gq, 256, 0, stream>>>(xb, wqb, wkb, wvb, qb, kbf, vtb, M, D, D, 1);

  // 3) causal flash attention (swapped-QK, 4-way split-K, 2048 blocks)
  attn_kernel<<<2048, 256, 0, stream>>>(qb, kbf, vtb, aob);

  // 4) output projection -> fp32 d_out
  dim3 go(D / 128, M / 128, 1);
  gemm_bt<<<go, 256, 0, stream>>>(aob, wob, wob, wob, d_out, d_out, d_out, M, D, D, 0);
}